// Round 4
// baseline (58.506 us; speedup 1.0000x reference)
//
#include <hip/hip_runtime.h>

#define N_FEATS 256
#define HIDDEN  128
#define N_CLASS 64
#define BATCH   1024
#define K0      25
#define K1      10
#define N_HIST  5
#define M_TOTAL (BATCH + BATCH * K1)   // 11264 layer-0 rows
#define KDIM    512
#define N_NODES 100000

typedef unsigned short u16;
typedef short bf16x8 __attribute__((ext_vector_type(8)));
typedef _Float16 f16x8 __attribute__((ext_vector_type(8)));
typedef float f32x4 __attribute__((ext_vector_type(4)));

static __device__ __forceinline__ u16 f2bf(float f) {
    union { float f; unsigned int i; } v;
    v.f = f;
    unsigned int x = v.i;
    x += ((x >> 16) & 1u) + 0x7FFFu;   // round-to-nearest-even
    return (u16)(x >> 16);
}
static __device__ __forceinline__ unsigned int pack2(float lo, float hi) {
    return (unsigned int)f2bf(lo) | ((unsigned int)f2bf(hi) << 16);
}
static __device__ __forceinline__ u16 f2h(float f) {
    union { _Float16 h; u16 u; } v;
    v.h = (_Float16)f;                 // v_cvt_f16_f32, RTE
    return v.u;
}
// Dual-width int load: little-endian low word == value for both int32/int64.
static __device__ __forceinline__ int loadI(const void* p, long long i, int f64) {
    const char* cp = (const char*)p + (f64 ? (i << 3) : (i << 2));
    return *(const int*)cp;
}

// ---------------------------------------------------------------------------
// int64-vs-int32 detection (odd int32 slots of nodes all zero => int64).
// ---------------------------------------------------------------------------
__global__ void k_detect(const void* __restrict__ nodes, int* __restrict__ flag) {
    if (threadIdx.x == 0 && blockIdx.x == 0) {
        const int* p = (const int*)nodes;
        int f = 1;
        for (int i = 0; i < 8; ++i)
            if (p[2 * i + 1] != 0) f = 0;
        *flag = f;
    }
}

// ===========================================================================
// SPLIT-PROJECTION PATH:
//   P_bot[100000][128] f16 = f16(feats) @ f16(W0_bot)   (needed for ALL nodes)
//   H_top[11264][128]  f16 = f16(feats[sel]) @ f16(W0_top)  (only gathered rows)
// Then layer-0 rows are 256B gathers of P_bot + positional reads of H_top.
// ===========================================================================

// W0 fp32 (512x128) -> fp16 W0T2 (256x256):
//   rows 0..127:   W0T2[c][k]     = W0[k][c]        (W0_top^T, K=0..255)
//   rows 128..255: W0T2[128+c][k] = W0[256+k][c]    (W0_bot^T)
// Also folds the int64 detection (one thread) to save a launch.
__global__ void k_transpose_w0h(const float* __restrict__ W0, u16* __restrict__ W0T2,
                                const void* __restrict__ nodes, int* __restrict__ flag) {
    if (threadIdx.x == 0 && threadIdx.y == 0 && blockIdx.x == 0 && blockIdx.y == 0) {
        const int* p = (const int*)nodes;
        int f = 1;
        for (int i = 0; i < 8; ++i)
            if (p[2 * i + 1] != 0) f = 0;
        *flag = f;
    }
    __shared__ u16 tile[32][33];
    int tx = threadIdx.x;            // 0..31
    int ty = threadIdx.y;            // 0..7
    int k0 = blockIdx.x * 32;        // over K=512 (16 blocks)
    int n0 = blockIdx.y * 32;        // over N=128 (4 blocks)
#pragma unroll
    for (int i = 0; i < 32; i += 8)
        tile[ty + i][tx] = f2h(W0[(size_t)(k0 + ty + i) * HIDDEN + n0 + tx]);
    __syncthreads();
    int roff = (k0 >= 256) ? 128 : 0;
    int kk = k0 & 255;
#pragma unroll
    for (int i = 0; i < 32; i += 8)
        W0T2[(size_t)(n0 + ty + i + roff) * 256 + kk + tx] = tile[tx][ty + i];
}

// Bottom-half projection: P_bot[100000][128] f16.
// Persistent 768 blocks (3/CU): block owns 4-5 contiguous 32-row tiles.
// 8 waves x 16 output cols each; B-frags (32 VGPR) register-resident.
// __launch_bounds__(512,6) pins VGPR<=85 -> 3 blocks/CU so barrier/vmcnt
// stalls in one block hide under the other two. Double-buffered LDS A-tiles;
// output tile staged through the dead half and stored as dwordx4 rows.
#define TROWS      32
#define NTILES     3125               // 3125 * 32 = 100000 rows exactly
#define BOT_NBLK   768
__global__ __launch_bounds__(512, 6) void k_projbot(
        const float* __restrict__ feats,
        const u16* __restrict__ W0T2,
        u16* __restrict__ Pb) {
    __shared__ u16 Xs[2][TROWS][256 + 8];   // 2 x 16.9 KB
    const int tid = threadIdx.x;
    const int wv = tid >> 6;
    const int lane = tid & 63;
    const int m = lane & 15;
    const int q = lane >> 4;
    const int base = NTILES / BOT_NBLK;             // 4
    const int rem = NTILES - base * BOT_NBLK;       // 53
    const int bi = blockIdx.x;
    const int s0 = bi * base + (bi < rem ? bi : rem);
    const int cnt = base + (bi < rem ? 1 : 0);      // 4 or 5 (>= 2)

    // Loop-invariant B fragments: W0_bot^T rows 128+wv*16+m, K contiguous.
    f16x8 B0[8];
    {
        const u16* bb = W0T2 + (size_t)(128 + wv * 16 + m) * 256 + q * 8;
#pragma unroll
        for (int kk = 0; kk < 8; ++kk)
            B0[kk] = *(const f16x8*)(bb + kk * 32);
    }

    float4 st[4];
    const float* fbase = feats + (size_t)(wv * 4) * N_FEATS + lane * 4;

#define PROJ_ISSUE(t)                                                         \
    {                                                                         \
        const float* fp_ = fbase + (size_t)(t) * (TROWS * N_FEATS);           \
        _Pragma("unroll")                                                     \
        for (int i = 0; i < 4; ++i)                                           \
            st[i] = *(const float4*)(fp_ + (size_t)i * N_FEATS);              \
    }
#define PROJ_WRITE(b)                                                         \
    {                                                                         \
        _Pragma("unroll")                                                     \
        for (int i = 0; i < 4; ++i) {                                         \
            ushort4 pk;                                                       \
            pk.x = f2h(st[i].x); pk.y = f2h(st[i].y);                         \
            pk.z = f2h(st[i].z); pk.w = f2h(st[i].w);                         \
            *(ushort4*)&Xs[b][wv * 4 + i][lane * 4] = pk;                     \
        }                                                                     \
    }

    PROJ_ISSUE(s0);
    PROJ_WRITE(0);
    PROJ_ISSUE(s0 + 1);               // cnt >= 2 always, no OOB
    __syncthreads();

    int cur = 0;
    for (int tt = 0; tt < cnt; ++tt) {
        const int t = s0 + tt;
        f32x4 a0 = (f32x4){0.f,0.f,0.f,0.f};
        f32x4 a1 = (f32x4){0.f,0.f,0.f,0.f};
#pragma unroll
        for (int kk = 0; kk < 8; ++kk) {
            f16x8 f0 = *(const f16x8*)&Xs[cur][m][kk * 32 + q * 8];
            f16x8 f1 = *(const f16x8*)&Xs[cur][m + 16][kk * 32 + q * 8];
            a0 = __builtin_amdgcn_mfma_f32_16x16x32_f16(f0, B0[kk], a0, 0, 0, 0);
            a1 = __builtin_amdgcn_mfma_f32_16x16x32_f16(f1, B0[kk], a1, 0, 0, 0);
        }
        __syncthreads();               // all waves done reading Xs[cur]
        // Output tile (32x128 f16) -> dead buffer. D: row=q*4+r, col=lane&15.
#pragma unroll
        for (int r = 0; r < 4; ++r) {
            Xs[cur][q * 4 + r][wv * 16 + m]      = f2h(a0[r]);
            Xs[cur][16 + q * 4 + r][wv * 16 + m] = f2h(a1[r]);
        }
        if (tt + 1 < cnt) {
            PROJ_WRITE(cur ^ 1);
            if (tt + 2 < cnt) PROJ_ISSUE(t + 2);
        }
        __syncthreads();
        // Coalesced store: 512 threads x 16B cover the 32x128 f16 tile.
        {
            const int row0 = tid >> 4;             // 0..31
            const int c8 = (tid & 15) * 8;         // f16 column
            uint4 w = *(const uint4*)&Xs[cur][row0][c8];
            *(uint4*)(Pb + (size_t)(t * TROWS + row0) * 128 + c8) = w;
        }
        cur ^= 1;
    }
#undef PROJ_ISSUE
#undef PROJ_WRITE
}

// Top-half projection for the 11264 gathered rows only (proven k_layer0
// structure minus the neighbor mean). Row g<BATCH -> nodes[g]; else
// neighs1[g-BATCH]. Output H_top f16 [11264][128].
__global__ __launch_bounds__(512) void k_top(
        const float* __restrict__ feats,
        const void* __restrict__ nodes,
        const void* __restrict__ neighs1,
        const u16* __restrict__ W0T2,
        u16* __restrict__ Htop,
        const int* __restrict__ flag) {
    __shared__ u16 Xs[16][256 + 8];
    const int f64 = *flag;
    int wv = threadIdx.x >> 6;
    int lane = threadIdx.x & 63;
    int row0 = blockIdx.x * 16;
    int d = lane * 4;

#pragma unroll
    for (int i = 0; i < 2; ++i) {
        int lr = wv * 2 + i;
        int g = row0 + lr;
        int selfIdx = (g < BATCH) ? loadI(nodes, g, f64)
                                  : loadI(neighs1, g - BATCH, f64);
        float4 sv = *(const float4*)(feats + (size_t)selfIdx * N_FEATS + d);
        ushort4 pk;
        pk.x = f2h(sv.x); pk.y = f2h(sv.y); pk.z = f2h(sv.z); pk.w = f2h(sv.w);
        *(ushort4*)&Xs[lr][d] = pk;
    }
    __syncthreads();

    int m = lane & 15;
    int q = lane >> 4;
    f32x4 acc = (f32x4){0.f, 0.f, 0.f, 0.f};
    const u16* bbase = W0T2 + (size_t)(wv * 16 + m) * 256 + q * 8;
#pragma unroll
    for (int kk = 0; kk < 8; ++kk) {
        f16x8 af = *(const f16x8*)&Xs[m][kk * 32 + q * 8];
        f16x8 bf = *(const f16x8*)(bbase + kk * 32);
        acc = __builtin_amdgcn_mfma_f32_16x16x32_f16(af, bf, acc, 0, 0, 0);
    }
    int col = wv * 16 + m;
#pragma unroll
    for (int r = 0; r < 4; ++r)
        Htop[(size_t)(row0 + q * 4 + r) * 128 + col] = f2h(acc[r]);
}

// Fused gather + layer-1: one 256-thread block (4 waves) per batch row b.
// Stage A: the 11 layer-0 rows of b: relu(Htop[g] + mean_k Pb[idx_k] + b0);
//   Htop read positionally (no self gather). Wave layout per row: lane
//   m=lane&15 owns cols m*8..m*8+7, grp=lane>>4 handles neighbors 4k+grp;
//   cross-grp reduce via 2 shfl_xor steps.
// Stage B/C: identical math to the proven k_final, H sourced from LDS.
__global__ __launch_bounds__(256) void k_gf(
        const u16* __restrict__ Pb,
        const u16* __restrict__ Htop,
        const float* __restrict__ history,
        const void* __restrict__ neighs0,
        const void* __restrict__ neighs1,
        const void* __restrict__ neighs0_nb,
        const void* __restrict__ h_nodes,
        const float* __restrict__ b0,
        const float* __restrict__ W1,
        const float* __restrict__ b1,
        float* __restrict__ out,
        const int* __restrict__ flag) {
    __shared__ float Hs[11][128];
    __shared__ float hcat[2 * HIDDEN];
    __shared__ float red[256];
    const int f64 = *flag;
    const int tid = threadIdx.x;
    const int b = blockIdx.x;
    const int wv = tid >> 6;
    const int lane = tid & 63;
    const int m = lane & 15;
    const int grp = lane >> 4;

    // ---- Stage A: rows wv, wv+4, wv+8 (<11)
    for (int r = wv; r < 11; r += 4) {
        const void* nbp;
        long long nbo;
        int g;
        if (r == 0) {
            nbp = neighs0; nbo = (long long)b * K0; g = b;
        } else {
            int rr = b * K1 + (r - 1);
            nbp = neighs0_nb; nbo = (long long)rr * K0; g = BATCH + rr;
        }
        int idx[K0];
#pragma unroll
        for (int k = 0; k < K0; ++k) idx[k] = loadI(nbp, nbo + k, f64);

        float a[8];
#pragma unroll
        for (int i = 0; i < 8; ++i) a[i] = 0.f;
#pragma unroll
        for (int k = 0; k < 7; ++k) {
            int k1 = 4 * k + grp;
            if (k1 < K0) {
                f16x8 v = *(const f16x8*)(Pb + (size_t)idx[k1] * 128 + m * 8);
#pragma unroll
                for (int i = 0; i < 8; ++i) a[i] += (float)v[i];
            }
        }
#pragma unroll
        for (int i = 0; i < 8; ++i) {
            a[i] += __shfl_xor(a[i], 16);
            a[i] += __shfl_xor(a[i], 32);
        }
        if (grp == 0) {
            f16x8 sv = *(const f16x8*)(Htop + (size_t)g * 128 + m * 8);
            const float inv = 1.0f / (float)K0;
#pragma unroll
            for (int i = 0; i < 8; ++i) {
                float y = a[i] * inv + (float)sv[i] + b0[m * 8 + i];
                Hs[r][m * 8 + i] = y > 0.f ? y : 0.f;
            }
        }
    }
    __syncthreads();

    // ---- Stage B: half 0 does t=0..4 (+h1), half 1 does t=5..9 (+history).
    const int j = tid & 127;
    const int half = tid >> 7;
    float S = 0.f;
    if (half == 0) hcat[j] = Hs[0][j];
#pragma unroll
    for (int t = half * 5; t < half * 5 + 5; ++t) {
        int n1 = loadI(neighs1, b * K1 + t, f64);
        S += 0.5f * (Hs[1 + t][j] - history[(size_t)n1 * HIDDEN + j]);
    }
    if (half == 1) {
#pragma unroll
        for (int u = 0; u < N_HIST; ++u) {
            int hn = loadI(h_nodes, b * N_HIST + u, f64);
            S += history[(size_t)hn * HIDDEN + j];
        }
    }
    red[tid] = S;
    __syncthreads();
    if (half == 0)
        hcat[HIDDEN + j] = (red[j] + red[HIDDEN + j]) * (1.0f / 15.0f);
    __syncthreads();

    // ---- Stage C: 4 threads per class column, 64-length partial dots.
    const int n = tid & 63;
    const int seg = tid >> 6;
    float p = 0.f;
#pragma unroll 8
    for (int i = seg * 64; i < seg * 64 + 64; ++i)
        p += hcat[i] * W1[(size_t)i * N_CLASS + n];
    red[tid] = p;
    __syncthreads();
    if (tid < 64) {
        float a = red[tid] + red[tid + 64] + red[tid + 128] + red[tid + 192]
                + b1[tid];
        a = a > 0.f ? a : 0.f;
        out[(size_t)b * N_CLASS + tid] = a;
    }
}

// ===========================================================================
// MIDDLE TIER (proven 65.5us path): kept verbatim for ws too small for P.
// ===========================================================================
__global__ void k_transpose_w0(const float* __restrict__ W0, u16* __restrict__ W0T) {
    __shared__ u16 tile[32][33];
    int tx = threadIdx.x;
    int ty = threadIdx.y;
    int k0 = blockIdx.x * 32;
    int n0 = blockIdx.y * 32;
#pragma unroll
    for (int i = 0; i < 32; i += 8)
        tile[ty + i][tx] = f2bf(W0[(size_t)(k0 + ty + i) * HIDDEN + n0 + tx]);
    __syncthreads();
#pragma unroll
    for (int i = 0; i < 32; i += 8)
        W0T[(size_t)(n0 + ty + i) * KDIM + k0 + tx] = tile[tx][ty + i];
}

__global__ __launch_bounds__(512) void k_layer0(
        const float* __restrict__ feats,
        const void* __restrict__ nodes,
        const void* __restrict__ neighs0,
        const void* __restrict__ neighs1,
        const void* __restrict__ neighs0_nb,
        const u16* __restrict__ W0T,
        const float* __restrict__ b0,
        float* __restrict__ H,
        const int* __restrict__ flag) {
    __shared__ u16 Xs[16][KDIM + 8];
    const int f64 = *flag;
    int wv = threadIdx.x >> 6;
    int lane = threadIdx.x & 63;
    int row0 = blockIdx.x * 16;
    int d = lane * 4;

#pragma unroll
    for (int i = 0; i < 2; ++i) {
        int lr = wv * 2 + i;
        int g = row0 + lr;
        int selfIdx;
        const void* nbp;
        long long nbo;
        if (g < BATCH) {
            selfIdx = loadI(nodes, g, f64);
            nbp = neighs0; nbo = (long long)g * K0;
        } else {
            int rr = g - BATCH;
            selfIdx = loadI(neighs1, rr, f64);
            nbp = neighs0_nb; nbo = (long long)rr * K0;
        }
        int idx[K0];
#pragma unroll
        for (int k = 0; k < K0; ++k) idx[k] = loadI(nbp, nbo + k, f64);

        float4 sv = *(const float4*)(feats + (size_t)selfIdx * N_FEATS + d);
        float a0 = 0.f, a1 = 0.f, a2 = 0.f, a3 = 0.f;
#pragma unroll
        for (int k = 0; k < K0; ++k) {
            float4 v = *(const float4*)(feats + (size_t)idx[k] * N_FEATS + d);
            a0 += v.x; a1 += v.y; a2 += v.z; a3 += v.w;
        }
        const float inv = 1.0f / (float)K0;
        uint2 spk, mpk;
        spk.x = pack2(sv.x, sv.y);
        spk.y = pack2(sv.z, sv.w);
        mpk.x = pack2(a0 * inv, a1 * inv);
        mpk.y = pack2(a2 * inv, a3 * inv);
        *(uint2*)&Xs[lr][d] = spk;
        *(uint2*)&Xs[lr][N_FEATS + d] = mpk;
    }
    __syncthreads();

    int m = lane & 15;
    int q = lane >> 4;
    f32x4 acc = (f32x4){0.f, 0.f, 0.f, 0.f};
    const u16* bbase = W0T + (size_t)(wv * 16 + m) * KDIM + q * 8;
#pragma unroll
    for (int k0 = 0; k0 < KDIM; k0 += 32) {
        bf16x8 af = *(const bf16x8*)&Xs[m][k0 + q * 8];
        bf16x8 bf = *(const bf16x8*)(bbase + k0);
        acc = __builtin_amdgcn_mfma_f32_16x16x32_bf16(af, bf, acc, 0, 0, 0);
    }
    int col = wv * 16 + m;
    float bias = b0[col];
#pragma unroll
    for (int r = 0; r < 4; ++r) {
        float y = acc[r] + bias;
        y = y > 0.f ? y : 0.f;
        H[(size_t)(row0 + q * 4 + r) * HIDDEN + col] = y;
    }
}

__global__ __launch_bounds__(256) void k_final(
        const float* __restrict__ H,
        const float* __restrict__ history,
        const void* __restrict__ neighs1,
        const void* __restrict__ h_nodes,
        const float* __restrict__ W1,
        const float* __restrict__ b1,
        float* __restrict__ out,
        const int* __restrict__ flag) {
    __shared__ float hcat[2 * HIDDEN];
    __shared__ float red[256];
    const int f64 = *flag;
    const int tid = threadIdx.x;
    const int b = blockIdx.x;
    const int j = tid & 127;
    const int half = tid >> 7;

    float S = 0.f;
    if (half == 0) hcat[j] = H[(size_t)b * HIDDEN + j];
#pragma unroll
    for (int t = half * 5; t < half * 5 + 5; ++t) {
        float orig = H[(size_t)(BATCH + b * K1 + t) * HIDDEN + j];
        int n1 = loadI(neighs1, b * K1 + t, f64);
        float hist = history[(size_t)n1 * HIDDEN + j];
        S += 0.5f * (orig - hist);
    }
    if (half == 1) {
#pragma unroll
        for (int u = 0; u < N_HIST; ++u) {
            int hn = loadI(h_nodes, b * N_HIST + u, f64);
            S += history[(size_t)hn * HIDDEN + j];
        }
    }
    red[tid] = S;
    __syncthreads();
    if (half == 0)
        hcat[HIDDEN + j] = (red[j] + red[HIDDEN + j]) * (1.0f / 15.0f);
    __syncthreads();

    const int n = tid & 63;
    const int seg = tid >> 6;
    float p = 0.f;
#pragma unroll 8
    for (int i = seg * 64; i < seg * 64 + 64; ++i)
        p += hcat[i] * W1[(size_t)i * N_CLASS + n];
    red[tid] = p;
    __syncthreads();
    if (tid < 64) {
        float a = red[tid] + red[tid + 64] + red[tid + 128] + red[tid + 192]
                + b1[tid];
        a = a > 0.f ? a : 0.f;
        out[(size_t)b * N_CLASS + tid] = a;
    }
}

// ===========================================================================
// Fallback: known-good monolithic kernel (used only if ws too small).
// ===========================================================================
static __device__ __forceinline__ float loadF_m(const void* p, long long i, int fbf) {
    const char* cp = (const char*)p + (fbf ? (i << 1) : (i << 2));
    if (fbf) {
        union { unsigned int u; float f; } v;
        v.u = ((unsigned int)(*(const u16*)cp)) << 16;
        return v.f;
    }
    return *(const float*)cp;
}

__global__ __launch_bounds__(256) void k_fused(
        const void* __restrict__ feats,
        const void* __restrict__ history,
        const void* __restrict__ W0,
        const void* __restrict__ b0,
        const void* __restrict__ W1,
        const void* __restrict__ b1,
        const void* __restrict__ nodes,
        const void* __restrict__ neighs0,
        const void* __restrict__ neighs1,
        const void* __restrict__ neighs0_nb,
        const void* __restrict__ h_nodes,
        float* __restrict__ out) {
    __shared__ float W0s[32][128];
    __shared__ float Xs[11][KDIM];
    __shared__ float hcat[2 * HIDDEN];
    __shared__ float red[256];
    __shared__ int ibuf[K0 + 1];
    __shared__ int sflags[2];

    const int tid = threadIdx.x;
    const int b = blockIdx.x;

    if (tid == 0) {
        const int* ip = (const int*)nodes;
        int f = 1;
        for (int i = 0; i < 8; ++i)
            if (ip[2 * i + 1] != 0) f = 0;
        sflags[0] = f;
        const u16* qp = (const u16*)feats;
        int cnt = 0;
        for (int i = 0; i < 64; ++i) {
            int e = (qp[2 * i] >> 7) & 0xFF;
            if (e >= 90 && e <= 134) cnt++;
        }
        sflags[1] = (cnt >= 40) ? 1 : 0;
    }
    __syncthreads();
    const int f64 = sflags[0];
    const int fbf = sflags[1];

    for (int r = 0; r < 11; ++r) {
        __syncthreads();
        if (tid < K0) {
            long long nbo = (r == 0) ? ((long long)b * K0)
                                     : ((long long)(b * K1 + (r - 1)) * K0);
            const void* nbp = (r == 0) ? neighs0 : neighs0_nb;
            ibuf[tid] = loadI(nbp, nbo + tid, f64);
        } else if (tid == K0) {
            ibuf[K0] = (r == 0) ? loadI(nodes, b, f64)
                                : loadI(neighs1, b * K1 + (r - 1), f64);
        }
        __syncthreads();
        int sidx = ibuf[K0];
        Xs[r][tid] = loadF_m(feats, (long long)sidx * N_FEATS + tid, fbf);
        float s = 0.f;
#pragma unroll
        for (int k = 0; k < K0; ++k)
            s += loadF_m(feats, (long long)ibuf[k] * N_FEATS + tid, fbf);
        Xs[r][N_FEATS + tid] = s * (1.0f / (float)K0);
    }
    __syncthreads();

    const int c = tid & 127;
    const int ph = tid >> 7;
    float acc[11];
#pragma unroll
    for (int r = 0; r < 11; ++r) acc[r] = 0.f;

    for (int s = 0; s < 16; ++s) {
        __syncthreads();
#pragma unroll
        for (int i = 0; i < 16; ++i) {
            int idx = tid + 256 * i;
            int k = idx >> 7, cc = idx & 127;
            W0s[k][cc] = loadF_m(W0, (long long)(32 * s + k) * HIDDEN + cc, fbf);
        }
        __syncthreads();
        const int kb = 32 * s + 16 * ph;
#pragma unroll
        for (int r = 0; r < 11; ++r) {
            float a = 0.f;
#pragma unroll
            for (int j = 0; j < 16; ++j)
                a += Xs[r][kb + j] * W0s[16 * ph + j][c];
            acc[r] += a;
        }
    }

    float S = 0.f;
    float b0v = (tid < 128) ? loadF_m(b0, tid, fbf) : 0.f;
    for (int r = 0; r < 11; ++r) {
        __syncthreads();
        red[tid] = acc[r];
        __syncthreads();
        if (tid < 128) {
            float h = red[tid] + red[tid + 128] + b0v;
            h = h > 0.f ? h : 0.f;
            if (r == 0) {
                hcat[tid] = h;
            } else {
                int n1 = loadI(neighs1, b * K1 + (r - 1), f64);
                float hist = loadF_m(history, (long long)n1 * HIDDEN + tid, fbf);
                S += 0.5f * (h - hist);
            }
        }
    }
    if (tid < 128) {
#pragma unroll
        for (int u = 0; u < N_HIST; ++u) {
            int hn = loadI(h_nodes, b * N_HIST + u, f64);
            S += loadF_m(history, (long long)hn * HIDDEN + tid, fbf);
        }
        hcat[HIDDEN + tid] = S * (1.0f / 15.0f);
    }
    __syncthreads();

    const int n = tid & 63;
    const int seg = tid >> 6;
    float p = 0.f;
#pragma unroll 8
    for (int i = seg * 64; i < seg * 64 + 64; ++i)
        p += hcat[i] * loadF_m(W1, (long long)i * N_CLASS + n, fbf);
    red[tid] = p;
    __syncthreads();
    if (tid < 64) {
        float a = red[tid] + red[tid + 64] + red[tid + 128] + red[tid + 192]
                + loadF_m(b1, tid, fbf);
        a = a > 0.f ? a : 0.f;
        out[(long long)b * N_CLASS + tid] = a;
    }
}

// ---------------------------------------------------------------------------
extern "C" void kernel_launch(void* const* d_in, const int* in_sizes, int n_in,
                              void* d_out, int out_size, void* d_ws, size_t ws_size,
                              hipStream_t stream) {
    (void)out_size;
    const long long want[11] = {25600000, 12800000, 65536, 128, 16384, 64,
                                1024, 25600, 10240, 256000, 5120};
    const void* bp[11];
    for (int j = 0; j < 11; ++j) bp[j] = d_in[j < n_in ? j : 0];
    for (int j = 0; j < 11; ++j) {
        if (j < n_in && (long long)in_sizes[j] == want[j]) continue;
        for (int i = 0; i < n_in; ++i)
            if ((long long)in_sizes[i] == want[j]) { bp[j] = d_in[i]; break; }
    }

    // New-path ws layout:
    //   W0T2 f16 (131072 B) | Pb f16 (25,600,000 B) | Htop f16 (2,883,584 B) | flag
    const size_t PB_BYTES = (size_t)N_NODES * 128 * 2;      // 25,600,000
    const size_t HT_BYTES = (size_t)M_TOTAL * 128 * 2;      //  2,883,584
    const size_t OFF_PB   = 131072;
    const size_t OFF_HT   = OFF_PB + PB_BYTES;
    const size_t OFF_FLAG = OFF_HT + HT_BYTES;
    const size_t WS_NEW   = OFF_FLAG + 16;
    // Old-path ws layout: W0T bf16 (131072 B) | H fp32 (5767168 B) | flag
    const size_t WS_OLD  = 131072 + 5767168 + 16;

    if (ws_size >= WS_NEW) {
        char* ws = (char*)d_ws;
        u16* W0T2 = (u16*)ws;
        u16* Pb   = (u16*)(ws + OFF_PB);
        u16* Htop = (u16*)(ws + OFF_HT);
        int* flag = (int*)(ws + OFF_FLAG);

        k_transpose_w0h<<<dim3(16, 4), dim3(32, 8), 0, stream>>>(
            (const float*)bp[2], W0T2, bp[6], flag);
        k_projbot<<<BOT_NBLK, 512, 0, stream>>>((const float*)bp[0], W0T2, Pb);
        k_top<<<M_TOTAL / 16, 512, 0, stream>>>(
            (const float*)bp[0], bp[6], bp[8], W0T2, Htop, flag);
        k_gf<<<BATCH, 256, 0, stream>>>(
            Pb, Htop, (const float*)bp[1], bp[7], bp[8], bp[9], bp[10],
            (const float*)bp[3], (const float*)bp[4], (const float*)bp[5],
            (float*)d_out, flag);
        return;
    }

    if (ws_size >= WS_OLD) {   // proven previous path
        char* ws = (char*)d_ws;
        u16* W0T  = (u16*)ws;
        float* H  = (float*)(ws + 131072);
        int* flag = (int*)(ws + 131072 + 5767168);

        k_detect<<<1, 1, 0, stream>>>(bp[6], flag);
        k_transpose_w0<<<dim3(16, 4), dim3(32, 8), 0, stream>>>((const float*)bp[2], W0T);
        k_layer0<<<M_TOTAL / 16, 512, 0, stream>>>(
            (const float*)bp[0], bp[6], bp[7], bp[8], bp[9], W0T,
            (const float*)bp[3], H, flag);
        k_final<<<BATCH, 256, 0, stream>>>(
            H, (const float*)bp[1], bp[8], bp[10],
            (const float*)bp[4], (const float*)bp[5], (float*)d_out, flag);
        return;
    }

    k_fused<<<BATCH, 256, 0, stream>>>(
        bp[0], bp[1], bp[2], bp[3], bp[4], bp[5],
        bp[6], bp[7], bp[8], bp[9], bp[10], (float*)d_out);
}

// Round 5
// 56.724 us; speedup vs baseline: 1.0314x; 1.0314x over previous
//
#include <hip/hip_runtime.h>

#define N_FEATS 256
#define HIDDEN  128
#define N_CLASS 64
#define BATCH   1024
#define K0      25
#define K1      10
#define N_HIST  5
#define M_TOTAL (BATCH + BATCH * K1)   // 11264 layer-0 rows
#define KDIM    512
#define N_NODES 100000

typedef unsigned short u16;
typedef short bf16x8 __attribute__((ext_vector_type(8)));
typedef _Float16 f16x8 __attribute__((ext_vector_type(8)));
typedef float f32x4 __attribute__((ext_vector_type(4)));

static __device__ __forceinline__ u16 f2bf(float f) {
    union { float f; unsigned int i; } v;
    v.f = f;
    unsigned int x = v.i;
    x += ((x >> 16) & 1u) + 0x7FFFu;   // round-to-nearest-even
    return (u16)(x >> 16);
}
static __device__ __forceinline__ unsigned int pack2(float lo, float hi) {
    return (unsigned int)f2bf(lo) | ((unsigned int)f2bf(hi) << 16);
}
static __device__ __forceinline__ u16 f2h(float f) {
    union { _Float16 h; u16 u; } v;
    v.h = (_Float16)f;                 // v_cvt_f16_f32, RTE
    return v.u;
}
// Dual-width int load: little-endian low word == value for both int32/int64.
static __device__ __forceinline__ int loadI(const void* p, long long i, int f64) {
    const char* cp = (const char*)p + (f64 ? (i << 3) : (i << 2));
    return *(const int*)cp;
}

// ---------------------------------------------------------------------------
// int64-vs-int32 detection (odd int32 slots of nodes all zero => int64).
// ---------------------------------------------------------------------------
__global__ void k_detect(const void* __restrict__ nodes, int* __restrict__ flag) {
    if (threadIdx.x == 0 && blockIdx.x == 0) {
        const int* p = (const int*)nodes;
        int f = 1;
        for (int i = 0; i < 8; ++i)
            if (p[2 * i + 1] != 0) f = 0;
        *flag = f;
    }
}

// ===========================================================================
// PROJECTION PATH: P = feats @ [W0_top | W0_bot]  (100000 x 256, fp16), then
// layer-0 rows become pure gathers of 256B P-slices instead of 26KB of feats.
// ===========================================================================

// W0 fp32 (512x128) -> fp16 W0T2 (256x256):
//   W0T2[n'][k'] with n'<128:  W0[k'][n']        (top half, K rows 0..255)
//              with n'>=128:   W0[256+k'][n'-128] (bottom half, K rows 256..511)
// Also folds the int64 detection (one thread) to save a launch.
__global__ void k_transpose_w0h(const float* __restrict__ W0, u16* __restrict__ W0T2,
                                const void* __restrict__ nodes, int* __restrict__ flag) {
    if (threadIdx.x == 0 && threadIdx.y == 0 && blockIdx.x == 0 && blockIdx.y == 0) {
        const int* p = (const int*)nodes;
        int f = 1;
        for (int i = 0; i < 8; ++i)
            if (p[2 * i + 1] != 0) f = 0;
        *flag = f;
    }
    __shared__ u16 tile[32][33];
    int tx = threadIdx.x;            // 0..31
    int ty = threadIdx.y;            // 0..7
    int k0 = blockIdx.x * 32;        // over K=512 (16 blocks)
    int n0 = blockIdx.y * 32;        // over N=128 (4 blocks)
#pragma unroll
    for (int i = 0; i < 32; i += 8)
        tile[ty + i][tx] = f2h(W0[(size_t)(k0 + ty + i) * HIDDEN + n0 + tx]);
    __syncthreads();
    int roff = (k0 >= 256) ? 128 : 0;
    int kk = k0 & 255;
#pragma unroll
    for (int i = 0; i < 32; i += 8)
        W0T2[(size_t)(n0 + ty + i + roff) * 256 + kk + tx] = tile[tx][ty + i];
}

// Projection GEMM v6: P[100000][256] fp16 = f16(feats) @ f16(W0cat).
// KEY FIX vs v3/v4: no __syncthreads() in the main loop. hipcc drains
// vmcnt(0) before every __syncthreads-barrier, which killed the prefetch
// every epoch (feats streamed at ~2.2 TB/s). Here: raw s_barrier + explicit
// lgkmcnt(0) only; the prefetch loads' completion is enforced by the
// compiler's own COUNTED vmcnt wait at the stA/stB use. Loads for tile t+2
// stay in flight across the barrier -> true 2-deep pipeline.
// Structure: 512 persistent blocks (2/CU), 12-13 16-row tiles each (exact
// 6250 total). 8 waves x 32 output cols; B-frags (64 VGPR) block-resident.
// Accumulators stored DIRECTLY to P (no output-LDS round trip): per 16-lane
// group stores are 32B-contiguous, and each 512B P-row is fully written by
// the block -> L2 write-combines. One barrier per epoch.
#define PROJ6_NBLK 512
__global__ __launch_bounds__(512, 4) void k_proj6(
        const float* __restrict__ feats,
        const u16* __restrict__ W0T2,
        u16* __restrict__ P) {
    __shared__ u16 Xs[2][16][256 + 8];   // 2 x 8.25 KB, +8 u16 pad
    const int tid = threadIdx.x;
    const int wv = tid >> 6;
    const int lane = tid & 63;
    const int m = lane & 15;
    const int q = lane >> 4;
    const int bi = blockIdx.x;
    const int NT = N_NODES / 16;               // 6250 tiles exactly
    const int base = NT / PROJ6_NBLK;          // 12
    const int rem  = NT - base * PROJ6_NBLK;   // 106
    const int s0 = bi * base + (bi < rem ? bi : rem);
    const int cnt = base + (bi < rem ? 1 : 0); // 12 or 13 (>= 2)

    // Loop-invariant B fragments (W0T2 rows = output cols, K contiguous).
    f16x8 B0[8], B1[8];
    {
        const u16* bb = W0T2 + (size_t)(wv * 32 + m) * 256 + q * 8;
#pragma unroll
        for (int kk = 0; kk < 8; ++kk) {
            B0[kk] = *(const f16x8*)(bb + kk * 32);
            B1[kk] = *(const f16x8*)(bb + 16 * 256 + kk * 32);
        }
    }

    // Wave wv stages rows wv*2, wv*2+1 of each 16-row tile (1KB row/wave-load).
    const float* fbase = feats + (size_t)(wv * 2) * N_FEATS + lane * 4;
    float4 sA0, sA1, sB0, sB1;   // two named staging sets (rule: no runtime idx)

#define P6_ISSUE(S0v, S1v, t)                                         \
    {                                                                 \
        const float* fp_ = fbase + (size_t)(t) * (16 * N_FEATS);      \
        S0v = *(const float4*)(fp_);                                  \
        S1v = *(const float4*)(fp_ + N_FEATS);                        \
    }
#define P6_WRITE(bsel, S0v, S1v)                                      \
    {                                                                 \
        ushort4 p0, p1;                                               \
        p0.x = f2h(S0v.x); p0.y = f2h(S0v.y);                         \
        p0.z = f2h(S0v.z); p0.w = f2h(S0v.w);                         \
        p1.x = f2h(S1v.x); p1.y = f2h(S1v.y);                         \
        p1.z = f2h(S1v.z); p1.w = f2h(S1v.w);                         \
        *(ushort4*)&Xs[bsel][wv * 2][lane * 4] = p0;                  \
        *(ushort4*)&Xs[bsel][wv * 2 + 1][lane * 4] = p1;              \
    }

    P6_ISSUE(sA0, sA1, s0);
    P6_ISSUE(sB0, sB1, s0 + 1);
    P6_WRITE(0, sA0, sA1);                  // compiler waits sA (counted vmcnt)
    asm volatile("s_waitcnt lgkmcnt(0)" ::: "memory");
    __builtin_amdgcn_s_barrier();

    int cur = 0;
    for (int tt = 0; tt < cnt; ++tt) {
        const int t = s0 + tt;
        // ---- compute tile t from Xs[cur]
        f32x4 a0 = (f32x4){0.f, 0.f, 0.f, 0.f};
        f32x4 a1 = (f32x4){0.f, 0.f, 0.f, 0.f};
#pragma unroll
        for (int kk = 0; kk < 8; ++kk) {
            f16x8 af = *(const f16x8*)&Xs[cur][m][kk * 32 + q * 8];
            a0 = __builtin_amdgcn_mfma_f32_16x16x32_f16(af, B0[kk], a0, 0, 0, 0);
            a1 = __builtin_amdgcn_mfma_f32_16x16x32_f16(af, B1[kk], a1, 0, 0, 0);
        }
        // ---- direct store. D: row=q*4+r, col=lane&15 (per 16-col tile).
        {
            u16* prow = P + (size_t)(t * 16 + q * 4) * 256 + wv * 32 + m;
#pragma unroll
            for (int r = 0; r < 4; ++r) {
                prow[(size_t)r * 256]      = f2h(a0[r]);
                prow[(size_t)r * 256 + 16] = f2h(a1[r]);
            }
        }
        // ---- pipeline maintenance: issue t+2, then write t+1 into Xs[cur^1].
        if (tt + 1 < cnt) {
            if ((tt & 1) == 0) {            // t+1 data sits in sB
                if (tt + 2 < cnt) P6_ISSUE(sA0, sA1, t + 2);
                P6_WRITE(cur ^ 1, sB0, sB1);
            } else {                        // t+1 data sits in sA
                if (tt + 2 < cnt) P6_ISSUE(sB0, sB1, t + 2);
                P6_WRITE(cur ^ 1, sA0, sA1);
            }
        }
        asm volatile("s_waitcnt lgkmcnt(0)" ::: "memory");
        __builtin_amdgcn_s_barrier();       // NO vmcnt drain: prefetch survives
        cur ^= 1;
    }
#undef P6_ISSUE
#undef P6_WRITE
}

// Fused gather + layer-1: one 256-thread block (4 waves) per batch row b.
// Stage A: the 11 layer-0 rows of b (self + 10 neighbors), each as
//   relu(P_top[self] + mean_k P_bot[idx_k] + b0), gathering 256B fp16 slices.
//   Wave layout per row: lane m=lane&15 owns cols m*8..m*8+7, grp=lane>>4
//   handles neighbors 4k+grp; cross-grp reduce via 2 shfl_xor steps.
// Stage B/C: identical math to the proven k_final, H sourced from LDS.
__global__ __launch_bounds__(256) void k_gf(
        const u16* __restrict__ P,
        const float* __restrict__ history,
        const void* __restrict__ nodes,
        const void* __restrict__ neighs0,
        const void* __restrict__ neighs1,
        const void* __restrict__ neighs0_nb,
        const void* __restrict__ h_nodes,
        const float* __restrict__ b0,
        const float* __restrict__ W1,
        const float* __restrict__ b1,
        float* __restrict__ out,
        const int* __restrict__ flag) {
    __shared__ float Hs[11][128];
    __shared__ float hcat[2 * HIDDEN];
    __shared__ float red[256];
    const int f64 = *flag;
    const int tid = threadIdx.x;
    const int b = blockIdx.x;
    const int wv = tid >> 6;
    const int lane = tid & 63;
    const int m = lane & 15;
    const int grp = lane >> 4;

    // ---- Stage A: rows wv, wv+4, wv+8 (<11)
    for (int r = wv; r < 11; r += 4) {
        int selfIdx;
        const void* nbp;
        long long nbo;
        if (r == 0) {
            selfIdx = loadI(nodes, b, f64);
            nbp = neighs0; nbo = (long long)b * K0;
        } else {
            int rr = b * K1 + (r - 1);
            selfIdx = loadI(neighs1, rr, f64);
            nbp = neighs0_nb; nbo = (long long)rr * K0;
        }
        int idx[K0];
#pragma unroll
        for (int k = 0; k < K0; ++k) idx[k] = loadI(nbp, nbo + k, f64);

        float a[8];
#pragma unroll
        for (int i = 0; i < 8; ++i) a[i] = 0.f;
#pragma unroll
        for (int k = 0; k < 7; ++k) {
            int k1 = 4 * k + grp;
            if (k1 < K0) {
                f16x8 v = *(const f16x8*)(P + (size_t)idx[k1] * 256 + 128 + m * 8);
#pragma unroll
                for (int i = 0; i < 8; ++i) a[i] += (float)v[i];
            }
        }
#pragma unroll
        for (int i = 0; i < 8; ++i) {
            a[i] += __shfl_xor(a[i], 16);
            a[i] += __shfl_xor(a[i], 32);
        }
        if (grp == 0) {
            f16x8 sv = *(const f16x8*)(P + (size_t)selfIdx * 256 + m * 8);
            const float inv = 1.0f / (float)K0;
#pragma unroll
            for (int i = 0; i < 8; ++i) {
                float y = a[i] * inv + (float)sv[i] + b0[m * 8 + i];
                Hs[r][m * 8 + i] = y > 0.f ? y : 0.f;
            }
        }
    }
    __syncthreads();

    // ---- Stage B: half 0 does t=0..4 (+h1), half 1 does t=5..9 (+history).
    const int j = tid & 127;
    const int half = tid >> 7;
    float S = 0.f;
    if (half == 0) hcat[j] = Hs[0][j];
#pragma unroll
    for (int t = half * 5; t < half * 5 + 5; ++t) {
        int n1 = loadI(neighs1, b * K1 + t, f64);
        S += 0.5f * (Hs[1 + t][j] - history[(size_t)n1 * HIDDEN + j]);
    }
    if (half == 1) {
#pragma unroll
        for (int u = 0; u < N_HIST; ++u) {
            int hn = loadI(h_nodes, b * N_HIST + u, f64);
            S += history[(size_t)hn * HIDDEN + j];
        }
    }
    red[tid] = S;
    __syncthreads();
    if (half == 0)
        hcat[HIDDEN + j] = (red[j] + red[HIDDEN + j]) * (1.0f / 15.0f);
    __syncthreads();

    // ---- Stage C: 4 threads per class column, 64-length partial dots.
    const int n = tid & 63;
    const int seg = tid >> 6;
    float p = 0.f;
#pragma unroll 8
    for (int i = seg * 64; i < seg * 64 + 64; ++i)
        p += hcat[i] * W1[(size_t)i * N_CLASS + n];
    red[tid] = p;
    __syncthreads();
    if (tid < 64) {
        float a = red[tid] + red[tid + 64] + red[tid + 128] + red[tid + 192]
                + b1[tid];
        a = a > 0.f ? a : 0.f;
        out[(size_t)b * N_CLASS + tid] = a;
    }
}

// ===========================================================================
// MIDDLE TIER (proven 65.5us path): kept verbatim for ws too small for P.
// ===========================================================================
__global__ void k_transpose_w0(const float* __restrict__ W0, u16* __restrict__ W0T) {
    __shared__ u16 tile[32][33];
    int tx = threadIdx.x;
    int ty = threadIdx.y;
    int k0 = blockIdx.x * 32;
    int n0 = blockIdx.y * 32;
#pragma unroll
    for (int i = 0; i < 32; i += 8)
        tile[ty + i][tx] = f2bf(W0[(size_t)(k0 + ty + i) * HIDDEN + n0 + tx]);
    __syncthreads();
#pragma unroll
    for (int i = 0; i < 32; i += 8)
        W0T[(size_t)(n0 + ty + i) * KDIM + k0 + tx] = tile[tx][ty + i];
}

__global__ __launch_bounds__(512) void k_layer0(
        const float* __restrict__ feats,
        const void* __restrict__ nodes,
        const void* __restrict__ neighs0,
        const void* __restrict__ neighs1,
        const void* __restrict__ neighs0_nb,
        const u16* __restrict__ W0T,
        const float* __restrict__ b0,
        float* __restrict__ H,
        const int* __restrict__ flag) {
    __shared__ u16 Xs[16][KDIM + 8];
    const int f64 = *flag;
    int wv = threadIdx.x >> 6;
    int lane = threadIdx.x & 63;
    int row0 = blockIdx.x * 16;
    int d = lane * 4;

#pragma unroll
    for (int i = 0; i < 2; ++i) {
        int lr = wv * 2 + i;
        int g = row0 + lr;
        int selfIdx;
        const void* nbp;
        long long nbo;
        if (g < BATCH) {
            selfIdx = loadI(nodes, g, f64);
            nbp = neighs0; nbo = (long long)g * K0;
        } else {
            int rr = g - BATCH;
            selfIdx = loadI(neighs1, rr, f64);
            nbp = neighs0_nb; nbo = (long long)rr * K0;
        }
        int idx[K0];
#pragma unroll
        for (int k = 0; k < K0; ++k) idx[k] = loadI(nbp, nbo + k, f64);

        float4 sv = *(const float4*)(feats + (size_t)selfIdx * N_FEATS + d);
        float a0 = 0.f, a1 = 0.f, a2 = 0.f, a3 = 0.f;
#pragma unroll
        for (int k = 0; k < K0; ++k) {
            float4 v = *(const float4*)(feats + (size_t)idx[k] * N_FEATS + d);
            a0 += v.x; a1 += v.y; a2 += v.z; a3 += v.w;
        }
        const float inv = 1.0f / (float)K0;
        uint2 spk, mpk;
        spk.x = pack2(sv.x, sv.y);
        spk.y = pack2(sv.z, sv.w);
        mpk.x = pack2(a0 * inv, a1 * inv);
        mpk.y = pack2(a2 * inv, a3 * inv);
        *(uint2*)&Xs[lr][d] = spk;
        *(uint2*)&Xs[lr][N_FEATS + d] = mpk;
    }
    __syncthreads();

    int m = lane & 15;
    int q = lane >> 4;
    f32x4 acc = (f32x4){0.f, 0.f, 0.f, 0.f};
    const u16* bbase = W0T + (size_t)(wv * 16 + m) * KDIM + q * 8;
#pragma unroll
    for (int k0 = 0; k0 < KDIM; k0 += 32) {
        bf16x8 af = *(const bf16x8*)&Xs[m][k0 + q * 8];
        bf16x8 bf = *(const bf16x8*)(bbase + k0);
        acc = __builtin_amdgcn_mfma_f32_16x16x32_bf16(af, bf, acc, 0, 0, 0);
    }
    int col = wv * 16 + m;
    float bias = b0[col];
#pragma unroll
    for (int r = 0; r < 4; ++r) {
        float y = acc[r] + bias;
        y = y > 0.f ? y : 0.f;
        H[(size_t)(row0 + q * 4 + r) * HIDDEN + col] = y;
    }
}

__global__ __launch_bounds__(256) void k_final(
        const float* __restrict__ H,
        const float* __restrict__ history,
        const void* __restrict__ neighs1,
        const void* __restrict__ h_nodes,
        const float* __restrict__ W1,
        const float* __restrict__ b1,
        float* __restrict__ out,
        const int* __restrict__ flag) {
    __shared__ float hcat[2 * HIDDEN];
    __shared__ float red[256];
    const int f64 = *flag;
    const int tid = threadIdx.x;
    const int b = blockIdx.x;
    const int j = tid & 127;
    const int half = tid >> 7;

    float S = 0.f;
    if (half == 0) hcat[j] = H[(size_t)b * HIDDEN + j];
#pragma unroll
    for (int t = half * 5; t < half * 5 + 5; ++t) {
        float orig = H[(size_t)(BATCH + b * K1 + t) * HIDDEN + j];
        int n1 = loadI(neighs1, b * K1 + t, f64);
        float hist = history[(size_t)n1 * HIDDEN + j];
        S += 0.5f * (orig - hist);
    }
    if (half == 1) {
#pragma unroll
        for (int u = 0; u < N_HIST; ++u) {
            int hn = loadI(h_nodes, b * N_HIST + u, f64);
            S += history[(size_t)hn * HIDDEN + j];
        }
    }
    red[tid] = S;
    __syncthreads();
    if (half == 0)
        hcat[HIDDEN + j] = (red[j] + red[HIDDEN + j]) * (1.0f / 15.0f);
    __syncthreads();

    const int n = tid & 63;
    const int seg = tid >> 6;
    float p = 0.f;
#pragma unroll 8
    for (int i = seg * 64; i < seg * 64 + 64; ++i)
        p += hcat[i] * W1[(size_t)i * N_CLASS + n];
    red[tid] = p;
    __syncthreads();
    if (tid < 64) {
        float a = red[tid] + red[tid + 64] + red[tid + 128] + red[tid + 192]
                + b1[tid];
        a = a > 0.f ? a : 0.f;
        out[(size_t)b * N_CLASS + tid] = a;
    }
}

// ===========================================================================
// Fallback: known-good monolithic kernel (used only if ws too small).
// ===========================================================================
static __device__ __forceinline__ float loadF_m(const void* p, long long i, int fbf) {
    const char* cp = (const char*)p + (fbf ? (i << 1) : (i << 2));
    if (fbf) {
        union { unsigned int u; float f; } v;
        v.u = ((unsigned int)(*(const u16*)cp)) << 16;
        return v.f;
    }
    return *(const float*)cp;
}

__global__ __launch_bounds__(256) void k_fused(
        const void* __restrict__ feats,
        const void* __restrict__ history,
        const void* __restrict__ W0,
        const void* __restrict__ b0,
        const void* __restrict__ W1,
        const void* __restrict__ b1,
        const void* __restrict__ nodes,
        const void* __restrict__ neighs0,
        const void* __restrict__ neighs1,
        const void* __restrict__ neighs0_nb,
        const void* __restrict__ h_nodes,
        float* __restrict__ out) {
    __shared__ float W0s[32][128];
    __shared__ float Xs[11][KDIM];
    __shared__ float hcat[2 * HIDDEN];
    __shared__ float red[256];
    __shared__ int ibuf[K0 + 1];
    __shared__ int sflags[2];

    const int tid = threadIdx.x;
    const int b = blockIdx.x;

    if (tid == 0) {
        const int* ip = (const int*)nodes;
        int f = 1;
        for (int i = 0; i < 8; ++i)
            if (ip[2 * i + 1] != 0) f = 0;
        sflags[0] = f;
        const u16* qp = (const u16*)feats;
        int cnt = 0;
        for (int i = 0; i < 64; ++i) {
            int e = (qp[2 * i] >> 7) & 0xFF;
            if (e >= 90 && e <= 134) cnt++;
        }
        sflags[1] = (cnt >= 40) ? 1 : 0;
    }
    __syncthreads();
    const int f64 = sflags[0];
    const int fbf = sflags[1];

    for (int r = 0; r < 11; ++r) {
        __syncthreads();
        if (tid < K0) {
            long long nbo = (r == 0) ? ((long long)b * K0)
                                     : ((long long)(b * K1 + (r - 1)) * K0);
            const void* nbp = (r == 0) ? neighs0 : neighs0_nb;
            ibuf[tid] = loadI(nbp, nbo + tid, f64);
        } else if (tid == K0) {
            ibuf[K0] = (r == 0) ? loadI(nodes, b, f64)
                                : loadI(neighs1, b * K1 + (r - 1), f64);
        }
        __syncthreads();
        int sidx = ibuf[K0];
        Xs[r][tid] = loadF_m(feats, (long long)sidx * N_FEATS + tid, fbf);
        float s = 0.f;
#pragma unroll
        for (int k = 0; k < K0; ++k)
            s += loadF_m(feats, (long long)ibuf[k] * N_FEATS + tid, fbf);
        Xs[r][N_FEATS + tid] = s * (1.0f / (float)K0);
    }
    __syncthreads();

    const int c = tid & 127;
    const int ph = tid >> 7;
    float acc[11];
#pragma unroll
    for (int r = 0; r < 11; ++r) acc[r] = 0.f;

    for (int s = 0; s < 16; ++s) {
        __syncthreads();
#pragma unroll
        for (int i = 0; i < 16; ++i) {
            int idx = tid + 256 * i;
            int k = idx >> 7, cc = idx & 127;
            W0s[k][cc] = loadF_m(W0, (long long)(32 * s + k) * HIDDEN + cc, fbf);
        }
        __syncthreads();
        const int kb = 32 * s + 16 * ph;
#pragma unroll
        for (int r = 0; r < 11; ++r) {
            float a = 0.f;
#pragma unroll
            for (int j = 0; j < 16; ++j)
                a += Xs[r][kb + j] * W0s[16 * ph + j][c];
            acc[r] += a;
        }
    }

    float S = 0.f;
    float b0v = (tid < 128) ? loadF_m(b0, tid, fbf) : 0.f;
    for (int r = 0; r < 11; ++r) {
        __syncthreads();
        red[tid] = acc[r];
        __syncthreads();
        if (tid < 128) {
            float h = red[tid] + red[tid + 128] + b0v;
            h = h > 0.f ? h : 0.f;
            if (r == 0) {
                hcat[tid] = h;
            } else {
                int n1 = loadI(neighs1, b * K1 + (r - 1), f64);
                float hist = loadF_m(history, (long long)n1 * HIDDEN + tid, fbf);
                S += 0.5f * (h - hist);
            }
        }
    }
    if (tid < 128) {
#pragma unroll
        for (int u = 0; u < N_HIST; ++u) {
            int hn = loadI(h_nodes, b * N_HIST + u, f64);
            S += loadF_m(history, (long long)hn * HIDDEN + tid, fbf);
        }
        hcat[HIDDEN + tid] = S * (1.0f / 15.0f);
    }
    __syncthreads();

    const int n = tid & 63;
    const int seg = tid >> 6;
    float p = 0.f;
#pragma unroll 8
    for (int i = seg * 64; i < seg * 64 + 64; ++i)
        p += hcat[i] * loadF_m(W1, (long long)i * N_CLASS + n, fbf);
    red[tid] = p;
    __syncthreads();
    if (tid < 64) {
        float a = red[tid] + red[tid + 64] + red[tid + 128] + red[tid + 192]
                + loadF_m(b1, tid, fbf);
        a = a > 0.f ? a : 0.f;
        out[(long long)b * N_CLASS + tid] = a;
    }
}

// ---------------------------------------------------------------------------
extern "C" void kernel_launch(void* const* d_in, const int* in_sizes, int n_in,
                              void* d_out, int out_size, void* d_ws, size_t ws_size,
                              hipStream_t stream) {
    (void)out_size;
    const long long want[11] = {25600000, 12800000, 65536, 128, 16384, 64,
                                1024, 25600, 10240, 256000, 5120};
    const void* bp[11];
    for (int j = 0; j < 11; ++j) bp[j] = d_in[j < n_in ? j : 0];
    for (int j = 0; j < 11; ++j) {
        if (j < n_in && (long long)in_sizes[j] == want[j]) continue;
        for (int i = 0; i < n_in; ++i)
            if ((long long)in_sizes[i] == want[j]) { bp[j] = d_in[i]; break; }
    }

    // New-path ws layout: W0T2 f16 (131072 B) | P f16 (51,200,000 B) | flag
    const size_t P_BYTES = (size_t)N_NODES * 256 * 2;          // 51,200,000
    const size_t WS_NEW  = 131072 + P_BYTES + 16;
    // Old-path ws layout: W0T bf16 (131072 B) | H fp32 (5767168 B) | flag
    const size_t WS_OLD  = 131072 + 5767168 + 16;

    if (ws_size >= WS_NEW) {
        char* ws = (char*)d_ws;
        u16* W0T2 = (u16*)ws;
        u16* P    = (u16*)(ws + 131072);
        int* flag = (int*)(ws + 131072 + P_BYTES);

        k_transpose_w0h<<<dim3(16, 4), dim3(32, 8), 0, stream>>>(
            (const float*)bp[2], W0T2, bp[6], flag);
        k_proj6<<<PROJ6_NBLK, 512, 0, stream>>>((const float*)bp[0], W0T2, P);
        k_gf<<<BATCH, 256, 0, stream>>>(
            P, (const float*)bp[1], bp[6], bp[7], bp[8], bp[9], bp[10],
            (const float*)bp[3], (const float*)bp[4], (const float*)bp[5],
            (float*)d_out, flag);
        return;
    }

    if (ws_size >= WS_OLD) {   // proven previous path
        char* ws = (char*)d_ws;
        u16* W0T  = (u16*)ws;
        float* H  = (float*)(ws + 131072);
        int* flag = (int*)(ws + 131072 + 5767168);

        k_detect<<<1, 1, 0, stream>>>(bp[6], flag);
        k_transpose_w0<<<dim3(16, 4), dim3(32, 8), 0, stream>>>((const float*)bp[2], W0T);
        k_layer0<<<M_TOTAL / 16, 512, 0, stream>>>(
            (const float*)bp[0], bp[6], bp[7], bp[8], bp[9], W0T,
            (const float*)bp[3], H, flag);
        k_final<<<BATCH, 256, 0, stream>>>(
            H, (const float*)bp[1], bp[8], bp[10],
            (const float*)bp[4], (const float*)bp[5], (float*)d_out, flag);
        return;
    }

    k_fused<<<BATCH, 256, 0, stream>>>(
        bp[0], bp[1], bp[2], bp[3], bp[4], bp[5],
        bp[6], bp[7], bp[8], bp[9], bp[10], (float*)d_out);
}